// Round 7
// baseline (156.551 us; speedup 1.0000x reference)
//
#include <hip/hip_runtime.h>
#include <hip/hip_bf16.h>
#include <stdint.h>

// CapsuleLayer dynamic routing v7.
// b_r[b,j,i] = sum_k u_hat[b,j,i,k] * Vacc[b,j,k]  (Vacc = sum of prior v's)
// Lane = (j:0-31 | kh bit5). Thread owns 1 j, 8 k's, NB=2 batches.
// v7: counted-vmcnt software pipeline (T3/T4). Triple-buffered W tiles,
// prefetch distance 2, raw s_barrier + s_waitcnt vmcnt(4) (never 0 in the
// steady loop) so the global_load_lds stream stays in flight across
// barriers (v6's __syncthreads drained vmcnt(0) every iteration -> L2/L3
// latency on the critical path; route was 50us vs ~10us compute floor).
// Compile-time buffer indices (integral_constant 3-unroll) -> ds_read_b128
// with immediate offsets; 16 pre-XOR-swizzled read addresses in VGPRs.
// Epilogue: v6-proven LDS-transpose + coalesced atomics (WRITE 12.3MB).

#define I_TILE  36
#define NSLICE  32                    // 1152/36 -> grid 16*32 = 512 = 2 WG/CU
#define WJ      (1152 * 128)          // floats between j planes

template<int N> struct IC { static constexpr int v = N; };

template<int R>
__global__ __launch_bounds__(256)
void caps_route(const float* __restrict__ x,     // [128,1152,8]
                const float* __restrict__ W,     // [32,1152,16,8]
                const float* __restrict__ Vacc,  // [128,32,16]
                float* __restrict__ s)           // [128,32,16] zeroed
{
    __shared__ float Wt[3][4096];     // 3 x 16KB W_i tiles (48KB)
    __shared__ float xs[8 * 288];     // [bl][36*8], 9.2KB

    const int tid  = threadIdx.x;
    const int lane = tid & 63;
    const int wv   = tid >> 6;        // wave 0..3
    const int j    = lane & 31;
    const int kh   = lane >> 5;       // k half
    const int bg   = blockIdx.x / NSLICE;   // 0..15
    const int sl   = blockIdx.x % NSLICE;   // 0..31
    const int i0   = sl * I_TILE;
    const int b0   = bg * 8 + wv * 2;       // this wave's 2 batches

    // ---- pre-swizzled global sources for global_load_lds (v4-proven) ----
    // LDS byte q = (wv*4+t)*1024 + lane*16 (linear dest). Inverse swizzle:
    // row rr=q>>8, cb=(q&255)^((rr&15)<<4); js=rr&31; c=(rr>>5)*64+cb/4.
    const float* wsrc[4];
    #pragma unroll
    for (int t = 0; t < 4; ++t) {
        const int q  = (wv * 4 + t) * 1024 + lane * 16;
        const int rr = q >> 8;
        const int cb = (q & 255) ^ ((rr & 15) << 4);
        const int js = rr & 31;
        const int c  = (rr >> 5) * 64 + (cb >> 2);
        wsrc[t] = W + (size_t)js * WJ + c;
    }

    auto stage = [&](int buf, int i) {
        #pragma unroll
        for (int t = 0; t < 4; ++t)
            __builtin_amdgcn_global_load_lds(
                (const __attribute__((address_space(1))) uint32_t*)
                    (wsrc[t] + (size_t)i * 128),
                (__attribute__((address_space(3))) uint32_t*)
                    &Wt[buf][(wv * 4 + t) * 256],
                16, 0, 0);
    };

    stage(0, i0);
    stage(1, i0 + 1);

    // ---- x slice -> LDS (576 float4s, coalesced) ----
    for (int cf = tid; cf < 576; cf += 256) {
        const int bl = cf / 72;
        const int rm = cf - bl * 72;
        float4 v = *reinterpret_cast<const float4*>(
            x + ((size_t)(bg * 8 + bl) * 1152 + i0) * 8 + rm * 4);
        *reinterpret_cast<float4*>(xs + bl * 288 + rm * 4) = v;
    }

    // Vacc fragment, prescaled to log2 domain
    float Vr[2][8];
    if (R > 0) {
        #pragma unroll
        for (int bb = 0; bb < 2; ++bb) {
            const float* vp =
                Vacc + ((size_t)(b0 + bb) * 32 + j) * 16 + kh * 8;
            const float4 va = *reinterpret_cast<const float4*>(vp);
            const float4 vb = *reinterpret_cast<const float4*>(vp + 4);
            Vr[bb][0] = va.x * 1.44269504f; Vr[bb][1] = va.y * 1.44269504f;
            Vr[bb][2] = va.z * 1.44269504f; Vr[bb][3] = va.w * 1.44269504f;
            Vr[bb][4] = vb.x * 1.44269504f; Vr[bb][5] = vb.y * 1.44269504f;
            Vr[bb][6] = vb.z * 1.44269504f; Vr[bb][7] = vb.w * 1.44269504f;
        }
    }

    float sacc[2][8];
    #pragma unroll
    for (int bb = 0; bb < 2; ++bb)
        #pragma unroll
        for (int kk = 0; kk < 8; ++kk) sacc[bb][kk] = 0.0f;

    // 16 read addresses (lane row + XOR swizzle), buffer chosen by imm offset
    const int sw = (j & 15) << 4;
    const char* ra[16];
    {
        const char* rb =
            reinterpret_cast<const char*>(&Wt[0][0]) + lane * 256;
        #pragma unroll
        for (int kk = 0; kk < 8; ++kk) {
            ra[2 * kk]     = rb + ((kk * 32)      ^ sw);
            ra[2 * kk + 1] = rb + ((kk * 32 + 16) ^ sw);
        }
    }

    __syncthreads();   // drains everything: tiles 0,1 + xs + Vacc ready

    // ---- pipelined body: wait(counted) -> barrier -> stage(i+2) -> compute
    auto body = [&](int ii, auto B, auto VM, bool do_stage) {
        if constexpr (decltype(VM)::v == 4)
            asm volatile("s_waitcnt vmcnt(4)" ::: "memory");
        else
            asm volatile("s_waitcnt vmcnt(0)" ::: "memory");
        __builtin_amdgcn_s_barrier();
        asm volatile("" ::: "memory");

        constexpr int BUF = decltype(B)::v;
        constexpr int NB  = (BUF + 2) % 3;
        if (do_stage) stage(NB, i0 + ii + 2);

        float4 xa[2], xb[2];
        #pragma unroll
        for (int bb = 0; bb < 2; ++bb) {
            const float* xp = xs + (wv * 2 + bb) * 288 + ii * 8;
            xa[bb] = *reinterpret_cast<const float4*>(xp);
            xb[bb] = *reinterpret_cast<const float4*>(xp + 4);
        }

        float u[2][8];
        #pragma unroll
        for (int kk = 0; kk < 8; ++kk) {
            const float4 w0 = *reinterpret_cast<const float4*>(
                ra[2 * kk] + BUF * 16384);
            const float4 w1 = *reinterpret_cast<const float4*>(
                ra[2 * kk + 1] + BUF * 16384);
            #pragma unroll
            for (int bb = 0; bb < 2; ++bb) {
                float acc;
                acc = w0.x * xa[bb].x;
                acc = fmaf(w0.y, xa[bb].y, acc);
                acc = fmaf(w0.z, xa[bb].z, acc);
                acc = fmaf(w0.w, xa[bb].w, acc);
                acc = fmaf(w1.x, xb[bb].x, acc);
                acc = fmaf(w1.y, xb[bb].y, acc);
                acc = fmaf(w1.z, xb[bb].z, acc);
                acc = fmaf(w1.w, xb[bb].w, acc);
                u[bb][kk] = acc;
            }
        }

        if (R == 0) {
            #pragma unroll
            for (int bb = 0; bb < 2; ++bb)
                #pragma unroll
                for (int kk = 0; kk < 8; ++kk)
                    sacc[bb][kk] = fmaf(0.03125f, u[bb][kk], sacc[bb][kk]);
        } else {
            float p0 = u[0][0] * Vr[0][0];
            float p1 = u[1][0] * Vr[1][0];
            #pragma unroll
            for (int kk = 1; kk < 8; ++kk) {
                p0 = fmaf(u[0][kk], Vr[0][kk], p0);
                p1 = fmaf(u[1][kk], Vr[1][kk], p1);
            }
            p0 += __shfl_xor(p0, 32);
            p1 += __shfl_xor(p1, 32);
            // paired softmax: kh=0 half does batch 0, kh=1 half batch 1
            const float pq = kh ? p1 : p0;
            const float e  = exp2f(pq);          // no max-subtract: |pq| small
            float den = e;
            den += __shfl_xor(den, 1);
            den += __shfl_xor(den, 2);
            den += __shfl_xor(den, 4);
            den += __shfl_xor(den, 8);
            den += __shfl_xor(den, 16);
            const float cf_own = e * __builtin_amdgcn_rcpf(den);
            const float cf_oth = __shfl_xor(cf_own, 32);
            const float cf0 = kh ? cf_oth : cf_own;
            const float cf1 = kh ? cf_own : cf_oth;
            #pragma unroll
            for (int kk = 0; kk < 8; ++kk) {
                sacc[0][kk] = fmaf(cf0, u[0][kk], sacc[0][kk]);
                sacc[1][kk] = fmaf(cf1, u[1][kk], sacc[1][kk]);
            }
        }
    };

    for (int g = 0; g < 11; ++g) {          // i = 0..32: always stage i+2
        const int i = 3 * g;
        body(i,     IC<0>{}, IC<4>{}, true);
        body(i + 1, IC<1>{}, IC<4>{}, true);
        body(i + 2, IC<2>{}, IC<4>{}, true);
    }
    body(33, IC<0>{}, IC<4>{}, true);       // stages i=35 into buf2
    body(34, IC<1>{}, IC<4>{}, false);
    body(35, IC<2>{}, IC<0>{}, false);      // final: full drain

    // ---- epilogue: per-wave LDS transpose -> COALESCED atomics (v6) ----
    // Wt[0] is dead for reads (last compute reads buf2); per-wave private
    // 4KB regions, no barrier needed. Swizzle k' = k ^ ((j>>1)&15).
    {
        float* ep = &Wt[0][0] + wv * 1024;
        #pragma unroll
        for (int bb = 0; bb < 2; ++bb)
            #pragma unroll
            for (int kk = 0; kk < 8; ++kk)
                ep[bb * 512 + j * 16 + ((kh * 8 + kk) ^ ((j >> 1) & 15))] =
                    sacc[bb][kk];

        float* sg = s + (size_t)b0 * 512;   // flat (b0..b0+1, j, k)
        #pragma unroll
        for (int c = 0; c < 16; ++c) {
            const int m   = c * 64 + lane;      // flat (bb, j, k)
            const int bb2 = m >> 9;
            const int j2  = (m >> 4) & 31;
            const int k2  = m & 15;
            const float v = ep[bb2 * 512 + j2 * 16 + (k2 ^ ((j2 >> 1) & 15))];
            atomicAdd(&sg[m], v);               // 64 contiguous addrs/instr
        }
    }
}

// MODE 0: Vacc = v, zero s;  MODE 1: Vacc += v, zero s;  MODE 2: out = v
template<int MODE>
__global__ __launch_bounds__(256)
void caps_squash(float* __restrict__ s,
                 float* __restrict__ Vacc,
                 float* __restrict__ out)
{
    const int t = blockIdx.x * 256 + threadIdx.x;   // (b,j,k), k fastest
    const float sv = s[t];
    float p = sv * sv;
    p += __shfl_xor(p, 1);
    p += __shfl_xor(p, 2);
    p += __shfl_xor(p, 4);
    p += __shfl_xor(p, 8);
    const float scale = p / ((1.0f + p) * sqrtf(p + 1e-7f));
    const float v = scale * sv;
    if (MODE == 0)      { Vacc[t] = v;  s[t] = 0.0f; }
    else if (MODE == 1) { Vacc[t] += v; s[t] = 0.0f; }
    else                { out[t] = v; }
}

extern "C" void kernel_launch(void* const* d_in, const int* in_sizes, int n_in,
                              void* d_out, int out_size, void* d_ws, size_t ws_size,
                              hipStream_t stream)
{
    const float* x = (const float*)d_in[0];   // [128,1152,8]
    const float* W = (const float*)d_in[1];   // [32,1152,16,8]
    float* out  = (float*)d_out;              // [128,32,16]
    float* Vacc = (float*)d_ws;               // 65536 floats
    float* s    = Vacc + 65536;               // 65536 floats

    hipMemsetAsync(s, 0, (size_t)65536 * sizeof(float), stream);

    dim3 grid(16 * NSLICE);   // 512 WGs = 2/CU exact
    dim3 blk(256);

    caps_route<0><<<grid, blk, 0, stream>>>(x, W, Vacc, s);
    caps_squash<0><<<256, 256, 0, stream>>>(s, Vacc, out);

    caps_route<1><<<grid, blk, 0, stream>>>(x, W, Vacc, s);
    caps_squash<1><<<256, 256, 0, stream>>>(s, Vacc, out);

    caps_route<2><<<grid, blk, 0, stream>>>(x, W, Vacc, s);
    caps_squash<2><<<256, 256, 0, stream>>>(s, Vacc, out);
}